// Round 1
// baseline (551.255 us; speedup 1.0000x reference)
//
#include <hip/hip_runtime.h>
#include <hip/hip_bf16.h>
#include <math.h>

// Problem constants
#define BB 8
#define HH 16
#define DD 1024
#define HD 64
#define PAST 8192
#define PAIRS (BB*HH)        // 128
#define CHUNKS 16
#define CHUNK (PAST/CHUNKS)  // 512
#define PART_STRIDE 66       // m, l, o[64]

// ---------------- Kernel A: QKV projection (GEMV, wave per output elem) ----
// qkv[mat][b][j] = sum_d x[b][d] * W[j][d] + bias[j]   (fp32)
__global__ __launch_bounds__(256) void qkv_kernel(
    const float* __restrict__ x,
    const float* __restrict__ Wq, const float* __restrict__ bq,
    const float* __restrict__ Wk, const float* __restrict__ bk,
    const float* __restrict__ Wv, const float* __restrict__ bv,
    float* __restrict__ qkv)
{
    int wid  = blockIdx.x * 4 + (threadIdx.x >> 6);   // [0, 24576)
    int lane = threadIdx.x & 63;
    int mat  = wid >> 13;            // 0=q 1=k 2=v
    int rem  = wid & 8191;
    int b    = rem >> 10;
    int j    = rem & 1023;
    const float* W    = (mat == 0) ? Wq : ((mat == 1) ? Wk : Wv);
    const float* bias = (mat == 0) ? bq : ((mat == 1) ? bk : bv);
    const float* xr = x + b * DD;
    const float* wr = W + (size_t)j * DD;
    float sum = 0.f;
    #pragma unroll
    for (int t = 0; t < 4; ++t) {
        float4 w4 = *(const float4*)(wr + t * 256 + lane * 4);
        float4 x4 = *(const float4*)(xr + t * 256 + lane * 4);
        sum = fmaf(x4.x, w4.x, sum);
        sum = fmaf(x4.y, w4.y, sum);
        sum = fmaf(x4.z, w4.z, sum);
        sum = fmaf(x4.w, w4.w, sum);
    }
    #pragma unroll
    for (int m = 32; m; m >>= 1) sum += __shfl_xor(sum, m);
    if (lane == 0)
        qkv[mat * (BB * DD) + b * DD + j] = sum + bias[j];
}

// ---------------- Kernel B: RoPE (pos = PAST), in-place on q,k -------------
__global__ __launch_bounds__(256) void rope_kernel(float* __restrict__ qkv)
{
    int tid = blockIdx.x * blockDim.x + threadIdx.x;   // [0, 4096)
    if (tid >= PAIRS * (HD / 2)) return;
    int i  = tid & 31;          // freq index [0,32)
    int bh = tid >> 5;          // pair [0,128)
    // Mimic JAX: inv_freq and ang computed/rounded in fp32, then exact trig.
    float invf = (float)pow(10000.0, -(double)i / 32.0);
    float angf = (float)PAST * invf;
    double ang = (double)angf;
    float c = (float)cos(ang), s = (float)sin(ang);
    float* q = qkv + bh * HD;
    float* k = qkv + BB * DD + bh * HD;
    float q0 = q[i], q1 = q[i + 32];
    q[i]      = q0 * c - q1 * s;
    q[i + 32] = q1 * c + q0 * s;
    float k0 = k[i], k1 = k[i + 32];
    k[i]      = k0 * c - k1 * s;
    k[i + 32] = k1 * c + k0 * s;
}

// ---------------- Kernel C: flash-decode partials over past KV -------------
// Two-phase per chunk: (1) scores -> LDS (no exp/rescale chain), block max;
// (2) single p-pass; (3) PV accumulate with pure FMAs.
// grid = PAIRS*CHUNKS blocks, 256 threads (4 waves). Wave handles 8 keys/iter:
// g = key-in-group (lane>>3), sl = dim slice (lane&7)*8.
__global__ __launch_bounds__(256) void attn_part_kernel(
    const float* __restrict__ past_k, const float* __restrict__ past_v,
    const float* __restrict__ qkv, float* __restrict__ part)
{
    int pair  = blockIdx.x >> 4;        // CHUNKS = 16
    int chunk = blockIdx.x & 15;
    int wave  = threadIdx.x >> 6;
    int lane  = threadIdx.x & 63;
    int g     = lane >> 3;              // key group 0..7
    int sl    = (lane & 7) * 8;         // dim slice start

    __shared__ float s_p[CHUNK];        // 512 raw scores, then p values
    __shared__ float s_m[4];
    __shared__ float red_o[4][64];
    __shared__ float red_l[4];

    const float* q = qkv + pair * HD;
    float ql[8];
    #pragma unroll
    for (int t = 0; t < 8; ++t) ql[t] = q[sl + t] * 0.125f;  // 1/sqrt(64)

    const float* kbase = past_k + ((size_t)pair * PAST + (size_t)chunk * CHUNK) * HD;
    const float* vbase = past_v + ((size_t)pair * PAST + (size_t)chunk * CHUNK) * HD;

    // ---- Phase 1: raw scores -> LDS, track max (no exp, no rescale) ----
    float m_loc = -1e30f;
    #pragma unroll 2
    for (int i = 0; i < CHUNK / 32; ++i) {       // 16 iters
        int key = i * 32 + wave * 8 + g;
        const float* kp = kbase + (size_t)key * HD + sl;
        float4 k0 = *(const float4*)(kp);
        float4 k1 = *(const float4*)(kp + 4);
        float s = 0.f;
        s = fmaf(ql[0], k0.x, s); s = fmaf(ql[1], k0.y, s);
        s = fmaf(ql[2], k0.z, s); s = fmaf(ql[3], k0.w, s);
        s = fmaf(ql[4], k1.x, s); s = fmaf(ql[5], k1.y, s);
        s = fmaf(ql[6], k1.z, s); s = fmaf(ql[7], k1.w, s);
        // reduce dims within group of 8 lanes -> score replicated in group
        s += __shfl_xor(s, 1); s += __shfl_xor(s, 2); s += __shfl_xor(s, 4);
        m_loc = fmaxf(m_loc, s);
        if ((lane & 7) == 0) s_p[key] = s;
    }
    // wave max (scores replicated within 8-lane groups -> only xor 8/16/32)
    m_loc = fmaxf(m_loc, __shfl_xor(m_loc, 8));
    m_loc = fmaxf(m_loc, __shfl_xor(m_loc, 16));
    m_loc = fmaxf(m_loc, __shfl_xor(m_loc, 32));
    if (lane == 0) s_m[wave] = m_loc;
    __syncthreads();
    float mblk = fmaxf(fmaxf(s_m[0], s_m[1]), fmaxf(s_m[2], s_m[3]));

    // ---- p-pass: 512 scores, 256 threads -> 2 each; partial l ----
    {
        int t0 = threadIdx.x;
        float p0 = __expf(s_p[t0] - mblk);
        float p1 = __expf(s_p[t0 + 256] - mblk);
        s_p[t0]       = p0;
        s_p[t0 + 256] = p1;
        float l_part = p0 + p1;
        #pragma unroll
        for (int m = 32; m; m >>= 1) l_part += __shfl_xor(l_part, m);
        if (lane == 0) red_l[wave] = l_part;
    }
    __syncthreads();

    // ---- Phase 2: PV accumulate (pure FMAs, broadcast LDS p-read) ----
    float acc[8];
    #pragma unroll
    for (int t = 0; t < 8; ++t) acc[t] = 0.f;
    #pragma unroll 4
    for (int i = 0; i < CHUNK / 32; ++i) {       // 16 iters
        int key = i * 32 + wave * 8 + g;
        const float* vp = vbase + (size_t)key * HD + sl;
        float4 v0 = *(const float4*)(vp);
        float4 v1 = *(const float4*)(vp + 4);
        float p = s_p[key];
        acc[0] = fmaf(p, v0.x, acc[0]);
        acc[1] = fmaf(p, v0.y, acc[1]);
        acc[2] = fmaf(p, v0.z, acc[2]);
        acc[3] = fmaf(p, v0.w, acc[3]);
        acc[4] = fmaf(p, v1.x, acc[4]);
        acc[5] = fmaf(p, v1.y, acc[5]);
        acc[6] = fmaf(p, v1.z, acc[6]);
        acc[7] = fmaf(p, v1.w, acc[7]);
    }
    // merge 8 key-groups (same dim slice lives at lanes with equal lane%8)
    #pragma unroll
    for (int t = 0; t < 8; ++t) {
        acc[t] += __shfl_xor(acc[t], 8);
        acc[t] += __shfl_xor(acc[t], 16);
        acc[t] += __shfl_xor(acc[t], 32);
    }
    if (lane < 8) {
        #pragma unroll
        for (int t = 0; t < 8; ++t) red_o[wave][lane * 8 + t] = acc[t];
    }
    __syncthreads();
    // all waves used the SAME mblk -> merge is a plain sum, no exp corrections
    if (threadIdx.x < 64) {
        int d = threadIdx.x;
        float o = red_o[0][d] + red_o[1][d] + red_o[2][d] + red_o[3][d];
        float* pp = part + (size_t)blockIdx.x * PART_STRIDE;
        pp[2 + d] = o;
        if (d == 0) {
            pp[0] = mblk;
            pp[1] = red_l[0] + red_l[1] + red_l[2] + red_l[3];
        }
    }
}

// ---------------- Kernel D: merge partials + new-token key/value -----------
__global__ __launch_bounds__(64) void attn_reduce_kernel(
    const float* __restrict__ part, const float* __restrict__ qkv,
    float* __restrict__ attn)
{
    int pair = blockIdx.x;
    int d    = threadIdx.x;
    const float* q  = qkv + pair * HD;
    const float* kn = qkv + BB * DD + pair * HD;
    const float* vn = qkv + 2 * BB * DD + pair * HD;
    // new-token score
    float s = q[d] * kn[d];
    #pragma unroll
    for (int m = 32; m; m >>= 1) s += __shfl_xor(s, m);
    s *= 0.125f;
    const float* pp = part + (size_t)pair * CHUNKS * PART_STRIDE;
    float m = s;
    for (int c = 0; c < CHUNKS; ++c) m = fmaxf(m, pp[c * PART_STRIDE]);
    float en = __expf(s - m);
    float l = en;             // new token contributes l = exp(s-m) * 1
    float o = en * vn[d];
    for (int c = 0; c < CHUNKS; ++c) {
        float e = __expf(pp[c * PART_STRIDE] - m);
        l += pp[c * PART_STRIDE + 1] * e;
        o += pp[c * PART_STRIDE + 2 + d] * e;
    }
    attn[pair * HD + d] = o / l;
}

// ---------------- Kernel E: output projection (fp32 out) -------------------
__global__ __launch_bounds__(256) void oproj_kernel(
    const float* __restrict__ attn, const float* __restrict__ Wo,
    const float* __restrict__ bo, float* __restrict__ out)
{
    int wid  = blockIdx.x * 4 + (threadIdx.x >> 6);   // [0, 8192)
    int lane = threadIdx.x & 63;
    int b = wid >> 10, j = wid & 1023;
    const float* ar = attn + b * DD;
    const float* wr = Wo + (size_t)j * DD;
    float sum = 0.f;
    #pragma unroll
    for (int t = 0; t < 4; ++t) {
        float4 w4 = *(const float4*)(wr + t * 256 + lane * 4);
        float4 a4 = *(const float4*)(ar + t * 256 + lane * 4);
        sum = fmaf(a4.x, w4.x, sum);
        sum = fmaf(a4.y, w4.y, sum);
        sum = fmaf(a4.z, w4.z, sum);
        sum = fmaf(a4.w, w4.w, sum);
    }
    #pragma unroll
    for (int m = 32; m; m >>= 1) sum += __shfl_xor(sum, m);
    if (lane == 0)
        out[b * DD + j] = sum + bo[j];
}

extern "C" void kernel_launch(void* const* d_in, const int* in_sizes, int n_in,
                              void* d_out, int out_size, void* d_ws, size_t ws_size,
                              hipStream_t stream) {
    const float* x      = (const float*)d_in[0];
    const float* Wq     = (const float*)d_in[1];
    const float* bq     = (const float*)d_in[2];
    const float* Wk     = (const float*)d_in[3];
    const float* bk     = (const float*)d_in[4];
    const float* Wv     = (const float*)d_in[5];
    const float* bv     = (const float*)d_in[6];
    const float* Wo     = (const float*)d_in[7];
    const float* bo     = (const float*)d_in[8];
    const float* past_k = (const float*)d_in[9];
    const float* past_v = (const float*)d_in[10];
    float* out = (float*)d_out;

    float* qkv  = (float*)d_ws;                        // 3*8192 floats
    float* part = qkv + 3 * BB * DD;                   // 2048*66 floats
    float* attn = part + PAIRS * CHUNKS * PART_STRIDE; // 8192 floats

    qkv_kernel<<<3 * BB * DD / 4, 256, 0, stream>>>(x, Wq, bq, Wk, bk, Wv, bv, qkv);
    rope_kernel<<<16, 256, 0, stream>>>(qkv);
    attn_part_kernel<<<PAIRS * CHUNKS, 256, 0, stream>>>(past_k, past_v, qkv, part);
    attn_reduce_kernel<<<PAIRS, 64, 0, stream>>>(part, qkv, attn);
    oproj_kernel<<<BB * DD / 4, 256, 0, stream>>>(attn, Wo, bo, out);
}